// Round 1
// baseline (2458.160 us; speedup 1.0000x reference)
//
#include <hip/hip_runtime.h>

// LatentODE fused fp32 baseline.
// B=8192, T=100, D=44, NH=64, L=8. One wave (64 lanes) per batch element.
// Lane j owns hidden unit j; weight columns in VGPRs; cross-lane broadcast
// via v_readlane (VALU) -> no LDS, no barriers.

constexpr int B_ = 8192, T_ = 100, D_ = 44, NH_ = 64, L_ = 8;

__device__ __forceinline__ float rl(float v, int lane) {
  return __int_as_float(__builtin_amdgcn_readlane(__float_as_int(v), lane));
}
__device__ __forceinline__ float fexp2(float x) { return __builtin_amdgcn_exp2f(x); }
__device__ __forceinline__ float frcp(float x) { return __builtin_amdgcn_rcpf(x); }
__device__ __forceinline__ float fexp(float x) { return fexp2(x * 1.44269504088896341f); }
__device__ __forceinline__ float tanh_f(float x) {
  // tanh(x) = 1 - 2/(exp(2x)+1); exp2 underflow/overflow saturate correctly.
  float e = fexp2(x * 2.88539008177792681f);
  return 1.0f - 2.0f * frcp(e + 1.0f);
}
__device__ __forceinline__ float elu_f(float x) {
  return x > 0.0f ? x : (fexp(x) - 1.0f);
}

// ---------------- Kernel A: backward RNN encoder + head + z0 + KL ----------
__global__ __launch_bounds__(256, 2) void rnn_kernel(
    const float* __restrict__ x, const float* __restrict__ mask,
    const float* __restrict__ eps,
    const float* __restrict__ Wi2h, const float* __restrict__ bi2h,
    const float* __restrict__ Wh2o, const float* __restrict__ bh2o,
    float* __restrict__ z0_out, float* __restrict__ loss) {
  const int b = (blockIdx.x * blockDim.x + threadIdx.x) >> 6;
  const int j = threadIdx.x & 63;
  if (b >= B_) return;

  // Lane j holds column j of Wi2h (108 VGPRs). Coalesced loads, L2-hot.
  float w[D_ + NH_];
#pragma unroll
  for (int k = 0; k < D_ + NH_; ++k) w[k] = Wi2h[k * NH_ + j];
  const float bj = bi2h[j];

  const float* xb = x + (size_t)b * T_ * D_;
  const float* mb = mask + (size_t)b * T_ * D_;

  float h = 0.0f;
#pragma unroll 1
  for (int s = 0; s < T_; ++s) {
    const int t = T_ - 1 - s;  // reversed-time scan
    float obs = 0.0f;
    if (j < D_) obs = xb[t * D_ + j] * mb[t * D_ + j];
    float a0 = bj, a1 = 0.0f, a2 = 0.0f, a3 = 0.0f;
#pragma unroll
    for (int k = 0; k < D_; k += 4) {
      a0 += rl(obs, k + 0) * w[k + 0];
      a1 += rl(obs, k + 1) * w[k + 1];
      a2 += rl(obs, k + 2) * w[k + 2];
      a3 += rl(obs, k + 3) * w[k + 3];
    }
#pragma unroll
    for (int k = 0; k < NH_; k += 4) {
      a0 += rl(h, k + 0) * w[D_ + k + 0];
      a1 += rl(h, k + 1) * w[D_ + k + 1];
      a2 += rl(h, k + 2) * w[D_ + k + 2];
      a3 += rl(h, k + 3) * w[D_ + k + 3];
    }
    h = tanh_f((a0 + a1) + (a2 + a3));
  }

  // out = h @ Wh2o + bh2o  (64x16). Lane l (clamped) owns column l&15.
  float who[NH_];
#pragma unroll
  for (int k = 0; k < NH_; ++k) who[k] = Wh2o[k * 16 + (j & 15)];
  float o0 = bh2o[j & 15], o1 = 0.0f, o2 = 0.0f, o3 = 0.0f;
#pragma unroll
  for (int k = 0; k < NH_; k += 4) {
    o0 += rl(h, k + 0) * who[k + 0];
    o1 += rl(h, k + 1) * who[k + 1];
    o2 += rl(h, k + 2) * who[k + 2];
    o3 += rl(h, k + 3) * who[k + 3];
  }
  const float o = (o0 + o1) + (o2 + o3);  // lane l<16: out[l]
  const float lv = __shfl(o, (j & 7) + 8, 64);  // logvar for lane j<8

  if (j < L_) {
    const float m = o;  // qz0_mean
    const float z0 = eps[b * L_ + j] * fexp(0.5f * lv) + m;
    z0_out[b * L_ + j] = z0;
    // KL term per latent dim, reduced over 8 lanes.
    float klt = -0.5f * lv + (fexp(lv) + m * m) * 0.5f - 0.5f;
    klt += __shfl_xor(klt, 1);
    klt += __shfl_xor(klt, 2);
    klt += __shfl_xor(klt, 4);
    if (j == 0) atomicAdd(loss, klt * (1.0f / (float)B_));
  }
}

// ------------- Kernel B: RK4 integration + decoder + masked NLL ------------
__global__ __launch_bounds__(256, 2) void rk4_kernel(
    const float* __restrict__ x, const float* __restrict__ mask,
    const float* __restrict__ z0buf,
    const float* __restrict__ Wf1, const float* __restrict__ bf1,
    const float* __restrict__ Wf2, const float* __restrict__ bf2,
    const float* __restrict__ Wf3, const float* __restrict__ bf3,
    const float* __restrict__ Wd1, const float* __restrict__ bd1,
    const float* __restrict__ Wd2, const float* __restrict__ bd2,
    float* __restrict__ loss) {
  const int b = (blockIdx.x * blockDim.x + threadIdx.x) >> 6;
  const int j = threadIdx.x & 63;
  if (b >= B_) return;
  const int d = (j < D_) ? j : 0;  // clamped output-dim role of this lane

  // Per-lane weight fragments (all in VGPRs).
  float wf1[8], wf2[64], wf3[8], wd1[8], wd2[64], b3r[8];
#pragma unroll
  for (int k = 0; k < 8; ++k) wf1[k] = Wf1[k * NH_ + j];
#pragma unroll
  for (int k = 0; k < 64; ++k) wf2[k] = Wf2[k * NH_ + j];
#pragma unroll
  for (int l = 0; l < 8; ++l) wf3[l] = Wf3[j * L_ + l];  // row j of Wf3
#pragma unroll
  for (int k = 0; k < 8; ++k) wd1[k] = Wd1[k * NH_ + j];
#pragma unroll
  for (int k = 0; k < 64; ++k) wd2[k] = Wd2[k * D_ + d];
#pragma unroll
  for (int l = 0; l < 8; ++l) b3r[l] = bf3[l];
  const float b1 = bf1[j], b2 = bf2[j], bd1j = bd1[j], bd2d = bd2[d];

  float z[8];
#pragma unroll
  for (int k = 0; k < 8; ++k) z[k] = z0buf[b * L_ + k];  // uniform values

  // f(z): 8 -> elu 64 -> elu 64 -> 8. Result ko[] is wave-uniform.
  auto feval = [&](const float (&zi)[8], float (&ko)[8]) {
    float h1 = b1;
#pragma unroll
    for (int k = 0; k < 8; ++k) h1 += zi[k] * wf1[k];
    h1 = elu_f(h1);
    float a0 = b2, a1 = 0.0f, a2 = 0.0f, a3 = 0.0f;
#pragma unroll
    for (int k = 0; k < 64; k += 4) {
      a0 += rl(h1, k + 0) * wf2[k + 0];
      a1 += rl(h1, k + 1) * wf2[k + 1];
      a2 += rl(h1, k + 2) * wf2[k + 2];
      a3 += rl(h1, k + 3) * wf2[k + 3];
    }
    float h2 = elu_f((a0 + a1) + (a2 + a3));
#pragma unroll
    for (int l = 0; l < 8; ++l) {
      float v = h2 * wf3[l];
      v += __shfl_xor(v, 1);
      v += __shfl_xor(v, 2);
      v += __shfl_xor(v, 4);
      v += __shfl_xor(v, 8);
      v += __shfl_xor(v, 16);
      v += __shfl_xor(v, 32);
      ko[l] = v + b3r[l];
    }
  };

  const float dt = 1.0f / (float)(T_ - 1);
  const float* xb = x + (size_t)b * T_ * D_;
  const float* mb = mask + (size_t)b * T_ * D_;
  float qacc = 0.0f;

#pragma unroll 1
  for (int t = 0; t < T_; ++t) {
    // Decoder on current z (pred_z[t]).
    float hd = bd1j;
#pragma unroll
    for (int k = 0; k < 8; ++k) hd += z[k] * wd1[k];
    hd = fmaxf(hd, 0.0f);
    float p0 = bd2d, p1 = 0.0f, p2 = 0.0f, p3 = 0.0f;
#pragma unroll
    for (int k = 0; k < 64; k += 4) {
      p0 += rl(hd, k + 0) * wd2[k + 0];
      p1 += rl(hd, k + 1) * wd2[k + 1];
      p2 += rl(hd, k + 2) * wd2[k + 2];
      p3 += rl(hd, k + 3) * wd2[k + 3];
    }
    const float px = (p0 + p1) + (p2 + p3);
    if (j < D_) {
      const float xv = xb[t * D_ + j];
      const float mv = mb[t * D_ + j];
      const float mx = xv * mv;
      const float upd = (mx != 0.0f) ? mx : px;
      const float df = xv - upd;
      qacc += df * df;
    }
    if (t == T_ - 1) break;

    // RK4 step with running k-accumulator (kacc = k1 + 2k2 + 2k3 + k4).
    float kacc[8], kc[8], zt[8];
    feval(z, kc);
#pragma unroll
    for (int k = 0; k < 8; ++k) { kacc[k] = kc[k]; zt[k] = z[k] + 0.5f * dt * kc[k]; }
    feval(zt, kc);
#pragma unroll
    for (int k = 0; k < 8; ++k) { kacc[k] += 2.0f * kc[k]; zt[k] = z[k] + 0.5f * dt * kc[k]; }
    feval(zt, kc);
#pragma unroll
    for (int k = 0; k < 8; ++k) { kacc[k] += 2.0f * kc[k]; zt[k] = z[k] + dt * kc[k]; }
    feval(zt, kc);
#pragma unroll
    for (int k = 0; k < 8; ++k) z[k] += (dt / 6.0f) * (kacc[k] + kc[k]);
  }

  // -logpx_b = (0.5/0.09)*sum(diff^2) - T*D*c0,  c0 = -0.5*(log(2pi)+2*log(0.3))
  float q = qacc;
  q += __shfl_xor(q, 1);
  q += __shfl_xor(q, 2);
  q += __shfl_xor(q, 4);
  q += __shfl_xor(q, 8);
  q += __shfl_xor(q, 16);
  q += __shfl_xor(q, 32);
  if (j == 0) {
    const float c0 = 0.28503427112126353f;
    const float neglogpx = q * (0.5f / 0.09f) - (float)(T_ * D_) * c0;
    atomicAdd(loss, neglogpx * (1.0f / (float)B_));
  }
}

extern "C" void kernel_launch(void* const* d_in, const int* in_sizes, int n_in,
                              void* d_out, int out_size, void* d_ws, size_t ws_size,
                              hipStream_t stream) {
  const float* x    = (const float*)d_in[0];
  const float* mask = (const float*)d_in[1];
  const float* eps  = (const float*)d_in[2];
  const float* Wi2h = (const float*)d_in[3];
  const float* bi2h = (const float*)d_in[4];
  const float* Wh2o = (const float*)d_in[5];
  const float* bh2o = (const float*)d_in[6];
  const float* Wf1  = (const float*)d_in[7];
  const float* bf1  = (const float*)d_in[8];
  const float* Wf2  = (const float*)d_in[9];
  const float* bf2  = (const float*)d_in[10];
  const float* Wf3  = (const float*)d_in[11];
  const float* bf3  = (const float*)d_in[12];
  const float* Wd1  = (const float*)d_in[13];
  const float* bd1  = (const float*)d_in[14];
  const float* Wd2  = (const float*)d_in[15];
  const float* bd2  = (const float*)d_in[16];

  float* loss = (float*)d_out;
  float* z0buf = (float*)d_ws;  // B*L floats = 256 KB

  hipMemsetAsync(loss, 0, sizeof(float), stream);

  const dim3 blk(256);             // 4 waves/block, 1 batch per wave
  const dim3 grd(B_ / 4);          // 8192 waves total

  rnn_kernel<<<grd, blk, 0, stream>>>(x, mask, eps, Wi2h, bi2h, Wh2o, bh2o,
                                      z0buf, loss);
  rk4_kernel<<<grd, blk, 0, stream>>>(x, mask, z0buf, Wf1, bf1, Wf2, bf2, Wf3,
                                      bf3, Wd1, bd1, Wd2, bd2, loss);
}

// Round 2
// 1175.203 us; speedup vs baseline: 2.0917x; 2.0917x over previous
//
#include <hip/hip_runtime.h>

// LatentODE: B=8192, T=100, D=44, NH=64, L=8.
// Kernel A (rnn): scalar fp32, one wave per batch (unchanged from R1, known-good).
// Kernel B (rk4): MFMA bf16 16x16x32. One wave owns M=16 batch rows; z kept in
// MFMA C-layout (f32); weights live in B-fragments (built in-register from f32
// globals); layer transitions via single-wave LDS transpose (DS in-order, no
// barriers). Decoder + masked-NLL fused into the step loop.

constexpr int B_ = 8192, T_ = 100, D_ = 44, NH_ = 64, L_ = 8;

typedef __bf16 bf16x8 __attribute__((ext_vector_type(8)));
typedef float f32x4 __attribute__((ext_vector_type(4)));
typedef unsigned short u16x8 __attribute__((ext_vector_type(8)));

__device__ __forceinline__ float rl(float v, int lane) {
  return __int_as_float(__builtin_amdgcn_readlane(__float_as_int(v), lane));
}
__device__ __forceinline__ float fexp2(float x) { return __builtin_amdgcn_exp2f(x); }
__device__ __forceinline__ float frcp(float x) { return __builtin_amdgcn_rcpf(x); }
__device__ __forceinline__ float fexp(float x) { return fexp2(x * 1.44269504088896341f); }
__device__ __forceinline__ float tanh_f(float x) {
  float e = fexp2(x * 2.88539008177792681f);
  return 1.0f - 2.0f * frcp(e + 1.0f);
}
__device__ __forceinline__ float elu_f(float x) {
  return x > 0.0f ? x : (fexp(x) - 1.0f);
}
__device__ __forceinline__ unsigned short f2bs(float x) {
  return __builtin_bit_cast(unsigned short, (__bf16)x);
}
__device__ __forceinline__ f32x4 mfma16(bf16x8 a, bf16x8 b, f32x4 c) {
  return __builtin_amdgcn_mfma_f32_16x16x32_bf16(a, b, c, 0, 0, 0);
}

// ---------------- Kernel A: backward RNN encoder + head + z0 + KL ----------
__global__ __launch_bounds__(256, 2) void rnn_kernel(
    const float* __restrict__ x, const float* __restrict__ mask,
    const float* __restrict__ eps,
    const float* __restrict__ Wi2h, const float* __restrict__ bi2h,
    const float* __restrict__ Wh2o, const float* __restrict__ bh2o,
    float* __restrict__ z0_out, float* __restrict__ loss) {
  const int b = (blockIdx.x * blockDim.x + threadIdx.x) >> 6;
  const int j = threadIdx.x & 63;
  if (b >= B_) return;

  float w[D_ + NH_];
#pragma unroll
  for (int k = 0; k < D_ + NH_; ++k) w[k] = Wi2h[k * NH_ + j];
  const float bj = bi2h[j];

  const float* xb = x + (size_t)b * T_ * D_;
  const float* mb = mask + (size_t)b * T_ * D_;

  float h = 0.0f;
#pragma unroll 1
  for (int s = 0; s < T_; ++s) {
    const int t = T_ - 1 - s;
    float obs = 0.0f;
    if (j < D_) obs = xb[t * D_ + j] * mb[t * D_ + j];
    float a0 = bj, a1 = 0.0f, a2 = 0.0f, a3 = 0.0f;
#pragma unroll
    for (int k = 0; k < D_; k += 4) {
      a0 += rl(obs, k + 0) * w[k + 0];
      a1 += rl(obs, k + 1) * w[k + 1];
      a2 += rl(obs, k + 2) * w[k + 2];
      a3 += rl(obs, k + 3) * w[k + 3];
    }
#pragma unroll
    for (int k = 0; k < NH_; k += 4) {
      a0 += rl(h, k + 0) * w[D_ + k + 0];
      a1 += rl(h, k + 1) * w[D_ + k + 1];
      a2 += rl(h, k + 2) * w[D_ + k + 2];
      a3 += rl(h, k + 3) * w[D_ + k + 3];
    }
    h = tanh_f((a0 + a1) + (a2 + a3));
  }

  float who[NH_];
#pragma unroll
  for (int k = 0; k < NH_; ++k) who[k] = Wh2o[k * 16 + (j & 15)];
  float o0 = bh2o[j & 15], o1 = 0.0f, o2 = 0.0f, o3 = 0.0f;
#pragma unroll
  for (int k = 0; k < NH_; k += 4) {
    o0 += rl(h, k + 0) * who[k + 0];
    o1 += rl(h, k + 1) * who[k + 1];
    o2 += rl(h, k + 2) * who[k + 2];
    o3 += rl(h, k + 3) * who[k + 3];
  }
  const float o = (o0 + o1) + (o2 + o3);
  const float lv = __shfl(o, (j & 7) + 8, 64);

  if (j < L_) {
    const float m = o;
    const float z0 = eps[b * L_ + j] * fexp(0.5f * lv) + m;
    z0_out[b * L_ + j] = z0;
    float klt = -0.5f * lv + (fexp(lv) + m * m) * 0.5f - 0.5f;
    klt += __shfl_xor(klt, 1);
    klt += __shfl_xor(klt, 2);
    klt += __shfl_xor(klt, 4);
    if (j == 0) atomicAdd(loss, klt * (1.0f / (float)B_));
  }
}

// ------------- Kernel B: MFMA RK4 + fused decoder + masked NLL -------------
// B-frag: lane holds B[k][n] with n = 16*tile + (lane&15), k = 32*ks + 8*(lane>>4) + i.
__device__ __forceinline__ bf16x8 load_bfrag(const float* __restrict__ W, int ldw,
                                             int kbase, int kmax, int n, bool nvalid) {
  bf16x8 f;
#pragma unroll
  for (int i = 0; i < 8; ++i) {
    const int k = kbase + i;
    const float v = (nvalid && k < kmax) ? W[k * ldw + n] : 0.0f;
    f[i] = (__bf16)v;
  }
  return f;
}

__global__ __launch_bounds__(64) void rk4_mfma_kernel(
    const float* __restrict__ x, const float* __restrict__ mask,
    const float* __restrict__ z0buf,
    const float* __restrict__ Wf1, const float* __restrict__ bf1,
    const float* __restrict__ Wf2, const float* __restrict__ bf2,
    const float* __restrict__ Wf3, const float* __restrict__ bf3,
    const float* __restrict__ Wd1, const float* __restrict__ bd1,
    const float* __restrict__ Wd2, const float* __restrict__ bd2,
    float* __restrict__ loss) {
  const int lane = threadIdx.x;      // 64-thread blocks: one wave per block
  const int c = lane & 15;           // C-layout column / A-layout row m
  const int q = lane >> 4;           // quad
  const int r0 = blockIdx.x * 16;    // this wave's batch-row base

  // Row stride 72 ushorts = 144 B: 16B-aligned rows, <=2-way bank aliasing (free).
  __shared__ __align__(16) unsigned short hbuf[16 * 72];
  __shared__ __align__(16) unsigned short zbuf[16 * 8];

  // ---- Weight B-fragments (built once; live in VGPRs for all 99 steps) ----
  bf16x8 B1[4], B2[4][2], B3[2], Bd1[4], Bd2[3][2];
#pragma unroll
  for (int tau = 0; tau < 4; ++tau) {
    B1[tau]  = load_bfrag(Wf1, NH_, 8 * q, L_, 16 * tau + c, true);
    Bd1[tau] = load_bfrag(Wd1, NH_, 8 * q, L_, 16 * tau + c, true);
#pragma unroll
    for (int ks = 0; ks < 2; ++ks)
      B2[tau][ks] = load_bfrag(Wf2, NH_, 32 * ks + 8 * q, NH_, 16 * tau + c, true);
  }
#pragma unroll
  for (int ks = 0; ks < 2; ++ks)
    B3[ks] = load_bfrag(Wf3, L_, 32 * ks + 8 * q, NH_, c, c < L_);
#pragma unroll
  for (int tau = 0; tau < 3; ++tau)
#pragma unroll
    for (int ks = 0; ks < 2; ++ks)
      Bd2[tau][ks] = load_bfrag(Wd2, D_, 32 * ks + 8 * q, NH_, 16 * tau + c, 16 * tau + c < D_);

  float bv1[4], bv2[4], bvd1[4], bvd2[3];
#pragma unroll
  for (int tau = 0; tau < 4; ++tau) {
    bv1[tau] = bf1[16 * tau + c];
    bv2[tau] = bf2[16 * tau + c];
    bvd1[tau] = bd1[16 * tau + c];
  }
#pragma unroll
  for (int tau = 0; tau < 3; ++tau)
    bvd2[tau] = (16 * tau + c < D_) ? bd2[16 * tau + c] : 0.0f;
  const float bv3 = (c < L_) ? bf3[c] : 0.0f;

  // ---- z state in C-layout f32: z[r] = z[row=4q+r][col=c], cols>=8 are 0 ----
  float z[4];
#pragma unroll
  for (int r = 0; r < 4; ++r)
    z[r] = (c < L_) ? z0buf[(size_t)(r0 + 4 * q + r) * L_ + c] : 0.0f;

  // C-layout -> bf16 A-fragment of a [16x8] z block (K padded to 32 with zeros).
  auto build_az = [&](const float (&zr)[4]) -> bf16x8 {
    if (c < L_) {
#pragma unroll
      for (int r = 0; r < 4; ++r) zbuf[(4 * q + r) * 8 + c] = f2bs(zr[r]);
    }
    bf16x8 a = {};
    if (q == 0) a = __builtin_bit_cast(bf16x8, *(const u16x8*)(zbuf + c * 8));
    return a;
  };

  auto read_afrag = [&](int ks) -> bf16x8 {
    return __builtin_bit_cast(bf16x8, *(const u16x8*)(hbuf + c * 72 + 32 * ks + 8 * q));
  };

  // f(z): 8 -> elu 64 -> elu 64 -> 8, output k in C-layout (cols>=8 zero).
  auto feval = [&](bf16x8 az, f32x4& kout) {
    f32x4 h[4];
#pragma unroll
    for (int tau = 0; tau < 4; ++tau) {
      f32x4 acc = {bv1[tau], bv1[tau], bv1[tau], bv1[tau]};
      h[tau] = mfma16(az, B1[tau], acc);
    }
#pragma unroll
    for (int tau = 0; tau < 4; ++tau)
#pragma unroll
      for (int r = 0; r < 4; ++r)
        hbuf[(4 * q + r) * 72 + 16 * tau + c] = f2bs(elu_f(h[tau][r]));
    bf16x8 a0 = read_afrag(0), a1 = read_afrag(1);
    f32x4 g[4];
#pragma unroll
    for (int tau = 0; tau < 4; ++tau) {
      f32x4 acc = {bv2[tau], bv2[tau], bv2[tau], bv2[tau]};
      acc = mfma16(a0, B2[tau][0], acc);
      g[tau] = mfma16(a1, B2[tau][1], acc);
    }
#pragma unroll
    for (int tau = 0; tau < 4; ++tau)
#pragma unroll
      for (int r = 0; r < 4; ++r)
        hbuf[(4 * q + r) * 72 + 16 * tau + c] = f2bs(elu_f(g[tau][r]));
    a0 = read_afrag(0); a1 = read_afrag(1);
    f32x4 kk = {bv3, bv3, bv3, bv3};
    kk = mfma16(a0, B3[0], kk);
    kout = mfma16(a1, B3[1], kk);
  };

  const float dt = 1.0f / (float)(T_ - 1);
  const float hdt = 0.5f * dt;
  float qacc = 0.0f;

#pragma unroll 1
  for (int t = 0; t < T_; ++t) {
    bf16x8 az = build_az(z);

    // Issue this step's x/mask loads early: latency hides behind the 4 fevals.
    float xv[3][4], mx[3][4];
#pragma unroll
    for (int tau = 0; tau < 3; ++tau) {
      const int n = 16 * tau + c;
#pragma unroll
      for (int r = 0; r < 4; ++r) {
        if (n < D_) {
          const size_t idx = ((size_t)(r0 + 4 * q + r) * T_ + t) * D_ + n;
          const float xt = x[idx];
          xv[tau][r] = xt;
          mx[tau][r] = xt * mask[idx];
        } else {
          xv[tau][r] = 0.0f; mx[tau][r] = 0.0f;
        }
      }
    }

    f32x4 k1 = {}, k2 = {}, k3 = {}, k4 = {};
    if (t < T_ - 1) {
      float zt[4];
      feval(az, k1);
#pragma unroll
      for (int r = 0; r < 4; ++r) zt[r] = z[r] + hdt * k1[r];
      feval(build_az(zt), k2);
#pragma unroll
      for (int r = 0; r < 4; ++r) zt[r] = z[r] + hdt * k2[r];
      feval(build_az(zt), k3);
#pragma unroll
      for (int r = 0; r < 4; ++r) zt[r] = z[r] + dt * k3[r];
      feval(build_az(zt), k4);
    }

    // Decoder on z_t (reuses az) + masked NLL accumulation.
    f32x4 hd[4];
#pragma unroll
    for (int tau = 0; tau < 4; ++tau) {
      f32x4 acc = {bvd1[tau], bvd1[tau], bvd1[tau], bvd1[tau]};
      hd[tau] = mfma16(az, Bd1[tau], acc);
    }
#pragma unroll
    for (int tau = 0; tau < 4; ++tau)
#pragma unroll
      for (int r = 0; r < 4; ++r)
        hbuf[(4 * q + r) * 72 + 16 * tau + c] = f2bs(fmaxf(hd[tau][r], 0.0f));
    bf16x8 a0 = read_afrag(0), a1 = read_afrag(1);
#pragma unroll
    for (int tau = 0; tau < 3; ++tau) {
      f32x4 p = {bvd2[tau], bvd2[tau], bvd2[tau], bvd2[tau]};
      p = mfma16(a0, Bd2[tau][0], p);
      p = mfma16(a1, Bd2[tau][1], p);
      if (16 * tau + c < D_) {
#pragma unroll
        for (int r = 0; r < 4; ++r) {
          const float m = mx[tau][r];
          const float upd = (m != 0.0f) ? m : p[r];
          const float df = xv[tau][r] - upd;
          qacc += df * df;
        }
      }
    }

    if (t < T_ - 1) {
#pragma unroll
      for (int r = 0; r < 4; ++r)
        z[r] += (dt / 6.0f) * (k1[r] + 2.0f * (k2[r] + k3[r]) + k4[r]);
    }
  }

  // Wave-reduce qacc; one atomic per wave (512 total).
  qacc += __shfl_xor(qacc, 1);
  qacc += __shfl_xor(qacc, 2);
  qacc += __shfl_xor(qacc, 4);
  qacc += __shfl_xor(qacc, 8);
  qacc += __shfl_xor(qacc, 16);
  qacc += __shfl_xor(qacc, 32);
  if (lane == 0) {
    const float c0 = 0.28503427112126353f;  // -0.5*(log(2pi)+2*log(0.3))
    const float contrib = qacc * (0.5f / 0.09f) - 16.0f * (float)(T_ * D_) * c0;
    atomicAdd(loss, contrib * (1.0f / (float)B_));
  }
}

extern "C" void kernel_launch(void* const* d_in, const int* in_sizes, int n_in,
                              void* d_out, int out_size, void* d_ws, size_t ws_size,
                              hipStream_t stream) {
  const float* x    = (const float*)d_in[0];
  const float* mask = (const float*)d_in[1];
  const float* eps  = (const float*)d_in[2];
  const float* Wi2h = (const float*)d_in[3];
  const float* bi2h = (const float*)d_in[4];
  const float* Wh2o = (const float*)d_in[5];
  const float* bh2o = (const float*)d_in[6];
  const float* Wf1  = (const float*)d_in[7];
  const float* bf1  = (const float*)d_in[8];
  const float* Wf2  = (const float*)d_in[9];
  const float* bf2  = (const float*)d_in[10];
  const float* Wf3  = (const float*)d_in[11];
  const float* bf3  = (const float*)d_in[12];
  const float* Wd1  = (const float*)d_in[13];
  const float* bd1  = (const float*)d_in[14];
  const float* Wd2  = (const float*)d_in[15];
  const float* bd2  = (const float*)d_in[16];

  float* loss = (float*)d_out;
  float* z0buf = (float*)d_ws;  // B*L floats = 256 KB

  hipMemsetAsync(loss, 0, sizeof(float), stream);

  rnn_kernel<<<dim3(B_ / 4), dim3(256), 0, stream>>>(
      x, mask, eps, Wi2h, bi2h, Wh2o, bh2o, z0buf, loss);
  rk4_mfma_kernel<<<dim3(B_ / 16), dim3(64), 0, stream>>>(
      x, mask, z0buf, Wf1, bf1, Wf2, bf2, Wf3, bf3, Wd1, bd1, Wd2, bd2, loss);
}